// Round 3
// baseline (1133.224 us; speedup 1.0000x reference)
//
#include <hip/hip_runtime.h>

typedef __bf16 bf16_t;
typedef __bf16 bf16x8 __attribute__((ext_vector_type(8)));
typedef float f32x4 __attribute__((ext_vector_type(4)));

#define MFMA16(a, b, c) __builtin_amdgcn_mfma_f32_16x16x32_bf16((a), (b), (c), 0, 0, 0)

__device__ __forceinline__ bf16_t f2b(float f) { return (bf16_t)f; }

// ---------------------------------------------------------------------------
// prep: W (1024x1024 f32, [c][n]) -> WT (bf16, [n][c]) for w_q,w_k,w_v,w_o
// ---------------------------------------------------------------------------
__global__ __launch_bounds__(256) void prep_kernel(
    const float* __restrict__ w0, const float* __restrict__ w1,
    const float* __restrict__ w2, const float* __restrict__ w3,
    bf16_t* __restrict__ WT)
{
    int z = blockIdx.z;
    const float* W = (z == 0) ? w0 : (z == 1) ? w1 : (z == 2) ? w2 : w3;
    bf16_t* dst = WT + ((size_t)z << 20);
    __shared__ float lds[64 * 65];
    int n0 = blockIdx.x * 64, c0 = blockIdx.y * 64;
    int t = threadIdx.x;
    int rl = t >> 2, q4 = t & 3;
    const float* src = W + (size_t)(c0 + rl) * 1024 + n0 + q4 * 16;
    float4 a0 = *(const float4*)(src);
    float4 a1 = *(const float4*)(src + 4);
    float4 a2 = *(const float4*)(src + 8);
    float4 a3 = *(const float4*)(src + 12);
    float* lr = lds + rl * 65 + q4 * 16;
    lr[0] = a0.x; lr[1] = a0.y; lr[2] = a0.z; lr[3] = a0.w;
    lr[4] = a1.x; lr[5] = a1.y; lr[6] = a1.z; lr[7] = a1.w;
    lr[8] = a2.x; lr[9] = a2.y; lr[10] = a2.z; lr[11] = a2.w;
    lr[12] = a3.x; lr[13] = a3.y; lr[14] = a3.z; lr[15] = a3.w;
    __syncthreads();
    bf16x8 o0, o1;
#pragma unroll
    for (int j = 0; j < 8; ++j) o0[j] = f2b(lds[(q4 * 16 + j) * 65 + rl]);
#pragma unroll
    for (int j = 0; j < 8; ++j) o1[j] = f2b(lds[(q4 * 16 + 8 + j) * 65 + rl]);
    bf16_t* dp = dst + (size_t)(n0 + rl) * 1024 + c0 + q4 * 16;
    *(bf16x8*)(dp) = o0;
    *(bf16x8*)(dp + 8) = o1;
}

// ---------------------------------------------------------------------------
// gemm: C[8192][1024] = A[8192][1024] @ W[1024][1024]  (W given as WT[n][c] bf16)
// mode 0: A=q f32   -> ws_q  bf16 [bh][l][64]
// mode 1: A=k f32   -> ws_k  bf16 [bh][l][64]
// mode 2: A=v f32   -> ws_vT bf16 [bh][k>>5][d][k&31]
// mode 3: A=ctx bf16-> tmp f32 [m][n]
// 128x128 tile, BK=32, 256 threads (4 waves, 2x2), mfma 16x16x32 bf16
// ---------------------------------------------------------------------------
__global__ __launch_bounds__(256) void gemm_kernel(
    const float* __restrict__ Aq, const float* __restrict__ Ak,
    const float* __restrict__ Av, const bf16_t* __restrict__ Actx,
    const bf16_t* __restrict__ WT,
    bf16_t* __restrict__ oq, bf16_t* __restrict__ ok, bf16_t* __restrict__ ovT,
    float* __restrict__ otmp, int mode_base)
{
    int mode = mode_base + blockIdx.z;
    const float* Af = (mode == 0) ? Aq : (mode == 1) ? Ak : Av;
    const bf16_t* Wp = WT + ((size_t)mode << 20);
    __shared__ __align__(16) unsigned char sm[16384];  // A 8KB | B 8KB
    int m0 = blockIdx.y * 128, n0 = blockIdx.x * 128;
    int t = threadIdx.x;
    int srow = t >> 1, shalf = t & 1;
    int wv = t >> 6, lane = t & 63, lrow = lane & 15, g = lane >> 4;
    int wm = (wv >> 1) * 64, wn = (wv & 1) * 64;
    f32x4 acc[4][4] = {};
    for (int kt = 0; kt < 32; ++kt) {
        int k0 = kt * 32;
        __syncthreads();
        {
            unsigned sab = srow * 64;
            int ch0 = (shalf * 2) ^ (srow & 3), ch1 = (shalf * 2 + 1) ^ (srow & 3);
            if (mode < 3) {
                const float* s = Af + (size_t)(m0 + srow) * 1024 + k0 + shalf * 16;
                float4 f0 = *(const float4*)(s);
                float4 f1 = *(const float4*)(s + 4);
                float4 f2 = *(const float4*)(s + 8);
                float4 f3 = *(const float4*)(s + 12);
                bf16x8 p0 = {f2b(f0.x), f2b(f0.y), f2b(f0.z), f2b(f0.w),
                             f2b(f1.x), f2b(f1.y), f2b(f1.z), f2b(f1.w)};
                bf16x8 p1 = {f2b(f2.x), f2b(f2.y), f2b(f2.z), f2b(f2.w),
                             f2b(f3.x), f2b(f3.y), f2b(f3.z), f2b(f3.w)};
                *(bf16x8*)(sm + sab + ch0 * 16) = p0;
                *(bf16x8*)(sm + sab + ch1 * 16) = p1;
            } else {
                const bf16_t* s = Actx + (size_t)(m0 + srow) * 1024 + k0 + shalf * 16;
                *(bf16x8*)(sm + sab + ch0 * 16) = *(const bf16x8*)(s);
                *(bf16x8*)(sm + sab + ch1 * 16) = *(const bf16x8*)(s + 8);
            }
            const bf16_t* sb = Wp + (size_t)(n0 + srow) * 1024 + k0 + shalf * 16;
            *(bf16x8*)(sm + 8192 + sab + ch0 * 16) = *(const bf16x8*)(sb);
            *(bf16x8*)(sm + 8192 + sab + ch1 * 16) = *(const bf16x8*)(sb + 8);
        }
        __syncthreads();
        bf16x8 av[4], bv[4];
#pragma unroll
        for (int i = 0; i < 4; ++i) {
            int ra = wm + i * 16 + lrow;
            av[i] = *(const bf16x8*)(sm + ra * 64 + ((g ^ (ra & 3)) * 16));
            int rb = wn + i * 16 + lrow;
            bv[i] = *(const bf16x8*)(sm + 8192 + rb * 64 + ((g ^ (rb & 3)) * 16));
        }
#pragma unroll
        for (int i = 0; i < 4; ++i)
#pragma unroll
            for (int j = 0; j < 4; ++j)
                acc[i][j] = MFMA16(av[i], bv[j], acc[i][j]);
    }
    // epilogue: D frag layout col = lane&15, row = 4*(lane>>4)+reg
#pragma unroll
    for (int i = 0; i < 4; ++i)
#pragma unroll
        for (int j = 0; j < 4; ++j)
#pragma unroll
            for (int r = 0; r < 4; ++r) {
                int m = m0 + wm + i * 16 + 4 * g + r;
                int n = n0 + wn + j * 16 + lrow;
                float vv = acc[i][j][r];
                if (mode == 3) {
                    otmp[(size_t)m * 1024 + n] = vv;
                } else {
                    int b = m >> 10, l = m & 1023, h = n >> 6, d = n & 63;
                    int bh = (b << 4) | h;
                    if (mode == 0)
                        oq[((size_t)bh * 1024 + l) * 64 + d] = f2b(vv);
                    else if (mode == 1)
                        ok[((size_t)bh * 1024 + l) * 64 + d] = f2b(vv);
                    else
                        ovT[(size_t)bh * 65536 + (size_t)(l >> 5) * 2048 + d * 32 + (l & 31)] = f2b(vv);
                }
            }
}

// ---------------------------------------------------------------------------
// attn: per (qt, bh): 8 waves x 16 q-rows. Full K (128KB, swizzled) in LDS.
// Pass 1: denom = sum(exp(s/8)) (no max-subtraction; scores are O(1)).
// Pass 2: recompute S, write attn fp32, P->LDS->A-frag, ctx += P@V.
// ---------------------------------------------------------------------------
__global__ __launch_bounds__(512) void attn_kernel(
    const bf16_t* __restrict__ wq, const bf16_t* __restrict__ wk,
    const bf16_t* __restrict__ wvT, const int* __restrict__ mask,
    float* __restrict__ attn, bf16_t* __restrict__ ctxo)
{
    __shared__ __align__(16) unsigned char sm[139264];  // K 128KB | P 8x1KB
    int qt = blockIdx.x, bh = blockIdx.y;
    int b = bh >> 4, h = bh & 15;
    int t = threadIdx.x, wv = t >> 6, lane = t & 63, lrow = lane & 15, g = lane >> 4;
    // stage K [1024][64] bf16, row = 128B = 8 chunks, chunk ^= (row&7)
    const bf16_t* Kb = wk + (size_t)bh * 65536;
#pragma unroll
    for (int it = 0; it < 16; ++it) {
        int cid = it * 512 + t;
        int krow = cid >> 3, ch = cid & 7;
        *(bf16x8*)(sm + krow * 128 + ((ch ^ (krow & 7)) * 16)) =
            *(const bf16x8*)(Kb + krow * 64 + ch * 8);
    }
    __syncthreads();
    int q0 = qt * 128 + wv * 16;
    const bf16_t* Qb = wq + ((size_t)bh * 1024 + q0 + lrow) * 64;
    bf16x8 aq0 = *(const bf16x8*)(Qb + 8 * g);
    bf16x8 aq1 = *(const bf16x8*)(Qb + 32 + 8 * g);
    const int* mrow = mask + ((size_t)b * 1024 + q0) * 1024;
    f32x4 zf = {0.f, 0.f, 0.f, 0.f};
    float denom[4] = {0.f, 0.f, 0.f, 0.f};
    // ---- pass 1 ----
    for (int kt = 0; kt < 64; ++kt) {
        int kc = kt * 16 + lrow;
        unsigned kb = kc * 128;
        bf16x8 bk0 = *(const bf16x8*)(sm + kb + ((g ^ (kc & 7)) * 16));
        bf16x8 bk1 = *(const bf16x8*)(sm + kb + (((4 + g) ^ (kc & 7)) * 16));
        f32x4 s = MFMA16(aq0, bk0, zf);
        s = MFMA16(aq1, bk1, s);
#pragma unroll
        for (int r = 0; r < 4; ++r) {
            float e = mrow[(size_t)(4 * g + r) * 1024 + kc] ? __expf(0.125f * s[r]) : 0.f;
            denom[r] += e;
        }
    }
#pragma unroll
    for (int r = 0; r < 4; ++r) {
        float e = denom[r];
        e += __shfl_xor(e, 1);
        e += __shfl_xor(e, 2);
        e += __shfl_xor(e, 4);
        e += __shfl_xor(e, 8);
        denom[r] = e;
    }
    float inv[4];
#pragma unroll
    for (int r = 0; r < 4; ++r) inv[r] = denom[r] > 0.f ? 1.f / denom[r] : 0.f;
    // ---- pass 2 ----
    float* Ao = attn + ((size_t)bh * 1024 + q0) * 1024;
    const bf16_t* Vb = wvT + (size_t)bh * 65536;
    unsigned pb = 131072 + wv * 1024;  // per-wave P tile 16x32 bf16
    f32x4 cacc[4] = {};
    for (int k2 = 0; k2 < 32; ++k2) {
#pragma unroll
        for (int f = 0; f < 2; ++f) {
            int kc = k2 * 32 + f * 16 + lrow;
            unsigned kb = kc * 128;
            bf16x8 bk0 = *(const bf16x8*)(sm + kb + ((g ^ (kc & 7)) * 16));
            bf16x8 bk1 = *(const bf16x8*)(sm + kb + (((4 + g) ^ (kc & 7)) * 16));
            f32x4 s = MFMA16(aq0, bk0, zf);
            s = MFMA16(aq1, bk1, s);
#pragma unroll
            for (int r = 0; r < 4; ++r) {
                int qr = 4 * g + r;
                float p = mrow[(size_t)qr * 1024 + kc] ? __expf(0.125f * s[r]) * inv[r] : 0.f;
                Ao[(size_t)qr * 1024 + kc] = p;
                int colw = f * 16 + lrow;
                unsigned byt = pb + qr * 64 + (((colw >> 3) ^ (qr & 3)) * 16) + (colw & 7) * 2;
                *(bf16_t*)(sm + byt) = f2b(p);
            }
        }
        __syncthreads();
        bf16x8 ap = *(const bf16x8*)(sm + pb + lrow * 64 + ((g ^ (lrow & 3)) * 16));
#pragma unroll
        for (int dt = 0; dt < 4; ++dt) {
            bf16x8 bv = *(const bf16x8*)(Vb + k2 * 2048 + (dt * 16 + lrow) * 32 + 8 * g);
            cacc[dt] = MFMA16(ap, bv, cacc[dt]);
        }
    }
    bf16_t* Co = ctxo + ((size_t)b * 1024 + q0) * 1024 + h * 64;
#pragma unroll
    for (int dt = 0; dt < 4; ++dt)
#pragma unroll
        for (int r = 0; r < 4; ++r)
            Co[(size_t)(4 * g + r) * 1024 + dt * 16 + lrow] = f2b(cacc[dt][r]);
}

// ---------------------------------------------------------------------------
// ln: out = LN(tmp + resid) * gamma + beta
// ---------------------------------------------------------------------------
__global__ __launch_bounds__(256) void ln_kernel(
    const float* __restrict__ tmp, const float* __restrict__ resid,
    const float* __restrict__ gamma, const float* __restrict__ beta,
    float* __restrict__ out)
{
    int row = blockIdx.x, t = threadIdx.x;
    const float4 x = *(const float4*)(tmp + (size_t)row * 1024 + t * 4);
    const float4 rs = *(const float4*)(resid + (size_t)row * 1024 + t * 4);
    float v0 = x.x + rs.x, v1 = x.y + rs.y, v2 = x.z + rs.z, v3 = x.w + rs.w;
    float s = v0 + v1 + v2 + v3;
    float q = v0 * v0 + v1 * v1 + v2 * v2 + v3 * v3;
#pragma unroll
    for (int m = 1; m < 64; m <<= 1) {
        s += __shfl_xor(s, m);
        q += __shfl_xor(q, m);
    }
    __shared__ float ps[4], pq[4];
    int wv = t >> 6;
    if ((t & 63) == 0) { ps[wv] = s; pq[wv] = q; }
    __syncthreads();
    s = ps[0] + ps[1] + ps[2] + ps[3];
    q = pq[0] + pq[1] + pq[2] + pq[3];
    float mean = s * (1.f / 1024.f);
    float var = q * (1.f / 1024.f) - mean * mean;
    float rstd = rsqrtf(var + 1e-6f);
    const float4 gm = *(const float4*)(gamma + t * 4);
    const float4 bt = *(const float4*)(beta + t * 4);
    float4 o;
    o.x = (v0 - mean) * rstd * gm.x + bt.x;
    o.y = (v1 - mean) * rstd * gm.y + bt.y;
    o.z = (v2 - mean) * rstd * gm.z + bt.z;
    o.w = (v3 - mean) * rstd * gm.w + bt.w;
    *(float4*)(out + (size_t)row * 1024 + t * 4) = o;
}

extern "C" void kernel_launch(void* const* d_in, const int* in_sizes, int n_in,
                              void* d_out, int out_size, void* d_ws, size_t ws_size,
                              hipStream_t stream) {
    const float* q = (const float*)d_in[0];
    const float* k = (const float*)d_in[1];
    const float* v = (const float*)d_in[2];
    const int* mask = (const int*)d_in[3];
    const float* w_q = (const float*)d_in[4];
    const float* w_k = (const float*)d_in[5];
    const float* w_v = (const float*)d_in[6];
    const float* w_o = (const float*)d_in[7];
    const float* gamma = (const float*)d_in[8];
    const float* beta = (const float*)d_in[9];
    float* out = (float*)d_out;
    float* attn = out + (size_t)8 * 1024 * 1024;

    unsigned char* ws = (unsigned char*)d_ws;
    bf16_t* ws_q = (bf16_t*)(ws);                    // 16 MB  [bh][l][64]
    bf16_t* ws_k = (bf16_t*)(ws + 16777216);         // 16 MB  [bh][l][64]
    bf16_t* ws_vT = (bf16_t*)(ws + 33554432);        // 16 MB  [bh][k>>5][d][k&31]
    bf16_t* ws_ctx = (bf16_t*)(ws + 50331648);       // 16 MB  [b*l][h*64+d]
    bf16_t* WT = (bf16_t*)(ws + 67108864);           // 8 MB   WTq,WTk,WTv,WTo
    float* tmp = (float*)(ws);                       // 32 MB, overlays dead ws_q/ws_k

    prep_kernel<<<dim3(16, 16, 4), 256, 0, stream>>>(w_q, w_k, w_v, w_o, WT);
    gemm_kernel<<<dim3(8, 64, 3), 256, 0, stream>>>(q, k, v, nullptr, WT,
                                                    ws_q, ws_k, ws_vT, nullptr, 0);
    attn_kernel<<<dim3(8, 128), 512, 0, stream>>>(ws_q, ws_k, ws_vT, mask, attn, ws_ctx);
    gemm_kernel<<<dim3(8, 64, 1), 256, 0, stream>>>(nullptr, nullptr, nullptr, ws_ctx, WT,
                                                    nullptr, nullptr, nullptr, tmp, 3);
    ln_kernel<<<8192, 256, 0, stream>>>(tmp, q, gamma, beta, out);
}